// Round 7
// baseline (234.126 us; speedup 1.0000x reference)
//
#include <hip/hip_runtime.h>

#define LMBDA 0.001f
#define NS_SY 4     // NS iters inv(sy): resid 0.8^16=0.028, enters lambda-damped C
#define NS_G  5     // NS iters inv(G1), Frobenius alpha (rate-only error)
#define NS_SX 4     // NS iters inv(sx): lambda-damped
#define OUTER 3     // outer Richardson iters
#define LDP 68      // padded stride for row-slice LDS matrices
#define SPLITS 8

// workspace layout (float offsets)
#define WS_R2   32768
#define WS_R4   36864
#define WS_T1   40960
#define WS_C    45056
#define WS_FYAT 49152
#define WS_CTR  53248
#define WS_PART 53312   // SPLITS x 32768 (2 mats x 64x256) partial buffers
#define WS_NEED ((WS_PART + SPLITS * 32768) * 4)

#define FMA4(ar, xs, b) { ar[0]=fmaf((xs),(b).x,ar[0]); ar[1]=fmaf((xs),(b).y,ar[1]); \
                          ar[2]=fmaf((xs),(b).z,ar[2]); ar[3]=fmaf((xs),(b).w,ar[3]); }

// C-tile += A[4ti..][:] * B[:][4tj..]; all f4 (b128) LDS reads
template<int SA, int SB>
__device__ __forceinline__ void mm64(const float* __restrict__ A,
                                     const float* __restrict__ B,
                                     int ti, int tj, float a[4][4]) {
    #pragma unroll 4
    for (int k = 0; k < 64; k += 4) {
        float4 av0 = *(const float4*)&A[(4 * ti + 0) * SA + k];
        float4 av1 = *(const float4*)&A[(4 * ti + 1) * SA + k];
        float4 av2 = *(const float4*)&A[(4 * ti + 2) * SA + k];
        float4 av3 = *(const float4*)&A[(4 * ti + 3) * SA + k];
        float4 b0 = *(const float4*)&B[(k + 0) * SB + 4 * tj];
        float4 b1 = *(const float4*)&B[(k + 1) * SB + 4 * tj];
        float4 b2 = *(const float4*)&B[(k + 2) * SB + 4 * tj];
        float4 b3 = *(const float4*)&B[(k + 3) * SB + 4 * tj];
        FMA4(a[0], av0.x, b0); FMA4(a[0], av0.y, b1); FMA4(a[0], av0.z, b2); FMA4(a[0], av0.w, b3);
        FMA4(a[1], av1.x, b0); FMA4(a[1], av1.y, b1); FMA4(a[1], av1.z, b2); FMA4(a[1], av1.w, b3);
        FMA4(a[2], av2.x, b0); FMA4(a[2], av2.y, b1); FMA4(a[2], av2.z, b2); FMA4(a[2], av2.w, b3);
        FMA4(a[3], av3.x, b0); FMA4(a[3], av3.y, b1); FMA4(a[3], av3.z, b2); FMA4(a[3], av3.w, b3);
    }
}

// ---- Newton-Schulz: X <- X(2I - M X), X0 = alpha*I. sM,sX pad; sY flat ----
__device__ __forceinline__ void ns_invert(float* sM, float* sX, float* sY,
                                          int iters, int ti, int tj,
                                          int tid, float alpha)
{
    for (int idx = tid; idx < 4096; idx += 256) {
        int i = idx >> 6, j = idx & 63;
        sX[i * LDP + j] = (i == j) ? alpha : 0.f;
    }
    __syncthreads();
    for (int it = 0; it < iters; ++it) {
        float y[4][4];
        #pragma unroll
        for (int r = 0; r < 4; ++r)
            #pragma unroll
            for (int c = 0; c < 4; ++c) y[r][c] = 0.f;
        mm64<LDP, LDP>(sM, sX, ti, tj, y);
        #pragma unroll
        for (int r = 0; r < 4; ++r) {
            float4 v = {y[r][0], y[r][1], y[r][2], y[r][3]};
            *(float4*)&sY[(4 * ti + r) * 64 + 4 * tj] = v;
        }
        __syncthreads();
        float z[4][4];
        #pragma unroll
        for (int r = 0; r < 4; ++r)
            #pragma unroll
            for (int c = 0; c < 4; ++c) z[r][c] = 0.f;
        mm64<LDP, 64>(sX, sY, ti, tj, z);
        __syncthreads();
        #pragma unroll
        for (int r = 0; r < 4; ++r) {
            float4 xv = *(const float4*)&sX[(4 * ti + r) * LDP + 4 * tj];
            xv.x = 2.f * xv.x - z[r][0];
            xv.y = 2.f * xv.y - z[r][1];
            xv.z = 2.f * xv.z - z[r][2];
            xv.w = 2.f * xv.w - z[r][3];
            *(float4*)&sX[(4 * ti + r) * LDP + 4 * tj] = xv;
        }
        __syncthreads();
    }
}

// ---------------- Kernel 1: A = tx@fx, Fy = ty@fy  (64x5000 @ 5000x256) ----
// partial mode: grid (8, SPLITS), block (bx,by) stores its split's partial.
// fallback:     grid (8, 27), atomicAdd into pre-zeroed region at pbase.
__global__ __launch_bounds__(256) void k1_gemm(
    const float* __restrict__ tx, const float* __restrict__ fx,
    const float* __restrict__ ty, const float* __restrict__ fy,
    float* __restrict__ ws, int nparts, int pbase)
{
    __shared__ float sT[64 * LDP];
    __shared__ float sF[64 * LDP];
    const int tid = threadIdx.x;
    const int ti = tid >> 4, tj = tid & 15;
    const int mat = blockIdx.x >> 2;
    const int m0 = (blockIdx.x & 3) << 6;
    const float* __restrict__ T = mat ? ty : tx;
    const float* __restrict__ F = mat ? fy : fx;
    float* __restrict__ Out = ws + pbase +
        (nparts > 1 ? (int)blockIdx.y * 32768 : 0) + mat * 16384;

    if (blockIdx.x == 0 && blockIdx.y == 0 && tid == 0)
        ((unsigned*)(ws + WS_CTR))[0] = 0u;   // zero k23's barrier counter

    float acc[4][4];
    #pragma unroll
    for (int r = 0; r < 4; ++r)
        #pragma unroll
        for (int c = 0; c < 4; ++c) acc[r][c] = 0.f;

    for (int sc = blockIdx.y; sc * 64 < 5000; sc += gridDim.y) {
        const int v0 = sc << 6;
        int vlen = 5000 - v0; if (vlen > 64) vlen = 64;
        #pragma unroll
        for (int w = 0; w < 4; ++w) {
            const int fidx = tid + (w << 8);
            const int row = fidx >> 4, q = fidx & 15;
            const int vv = q << 2;
            if (vv < vlen) {
                float4 val = *(const float4*)(T + (size_t)row * 5000 + v0 + vv);
                sT[(vv + 0) * LDP + row] = val.x;
                sT[(vv + 1) * LDP + row] = val.y;
                sT[(vv + 2) * LDP + row] = val.z;
                sT[(vv + 3) * LDP + row] = val.w;
            }
            if (row < vlen) {
                *(float4*)&sF[row * LDP + (q << 2)] =
                    *(const float4*)(F + (size_t)(v0 + row) * 256 + m0 + (q << 2));
            }
        }
        __syncthreads();
        for (int v = 0; v < vlen; ++v) {
            float4 av = *(const float4*)&sT[v * LDP + 4 * ti];
            float4 bv = *(const float4*)&sF[v * LDP + 4 * tj];
            FMA4(acc[0], av.x, bv); FMA4(acc[1], av.y, bv);
            FMA4(acc[2], av.z, bv); FMA4(acc[3], av.w, bv);
        }
        __syncthreads();
    }
    if (nparts > 1) {
        #pragma unroll
        for (int r = 0; r < 4; ++r) {
            float4 v = {acc[r][0], acc[r][1], acc[r][2], acc[r][3]};
            *(float4*)&Out[(4 * ti + r) * 256 + m0 + 4 * tj] = v;
        }
    } else {
        #pragma unroll
        for (int r = 0; r < 4; ++r)
            #pragma unroll
            for (int c = 0; c < 4; ++c)
                atomicAdd(&Out[(4 * ti + r) * 256 + m0 + 4 * tj + c], acc[r][c]);
    }
}

// ---------------- Kernel 23: fused prep + solve (4 blocks, dyn LDS) -------
// blk0: A-reduce, G1 syrk, Ginv=NS5 (all LDS-local); barrier-wait; solve.
// blk1: H1=sy^T sy; Sinv=NS(sy); C = Sinv*(Sinv^T D H1) -> ws
// blk2: P=NS(sx); R2/R4/T1 -> ws       blk3: A,Fy reduce; FyAT -> ws
// blk0 k3 layout (floats): cM1 0 | cR2 4096 | cR4 8192 | cGinv 12288 |
//   sE/sYy 16384 | sX/sXx 20480(pad) | cC/sAT 24832(pad) | sW/sG 29184(pad) |
//   sV 33536(128) -> 33664 floats
__global__ __launch_bounds__(256, 1) void k23_fused(
    float* __restrict__ ws,
    const float* __restrict__ sx, const float* __restrict__ sy,
    const float* __restrict__ ex, const float* __restrict__ ey,
    float* __restrict__ out, int nparts, int pbase)
{
    extern __shared__ __align__(16) float lds[];
    const int tid = threadIdx.x;
    const int ti = tid >> 4, tj = tid & 15;
    const int b = blockIdx.x;
    unsigned* ctr = (unsigned*)(ws + WS_CTR);

    if (b == 1) {
        float* s0 = lds;            // pad: sy
        float* s1 = lds + 4352;     // pad: NS X -> Sinv
        float* s2 = lds + 8704;     // flat: NS tmp -> Z
        float* s3 = lds + 12800;    // flat: H1
        float* sV = lds + 16896;    // ey
        for (int idx = tid; idx < 1024; idx += 256) {
            int i = idx >> 4, j4 = (idx & 15) << 2;
            *(float4*)&s0[i * LDP + j4] = *(const float4*)&sy[i * 64 + j4];
        }
        if (tid < 64) sV[tid] = ey[tid];
        __syncthreads();
        // H1 = sy^T sy (k-fixed outer product)
        {
            float h[4][4];
            #pragma unroll
            for (int r = 0; r < 4; ++r)
                #pragma unroll
                for (int c = 0; c < 4; ++c) h[r][c] = 0.f;
            for (int k = 0; k < 64; ++k) {
                float4 av = *(const float4*)&s0[k * LDP + 4 * ti];
                float4 bv = *(const float4*)&s0[k * LDP + 4 * tj];
                FMA4(h[0], av.x, bv); FMA4(h[1], av.y, bv);
                FMA4(h[2], av.z, bv); FMA4(h[3], av.w, bv);
            }
            #pragma unroll
            for (int r = 0; r < 4; ++r) {
                float4 v = {h[r][0], h[r][1], h[r][2], h[r][3]};
                *(float4*)&s3[(4 * ti + r) * 64 + 4 * tj] = v;
            }
        }
        __syncthreads();
        ns_invert(s0, s1, s2, NS_SY, ti, tj, tid, 1.0f);   // Sinv in s1
        // Z = Sinv^T * (D H1): Z[i][j] = sum_k Sinv[k][i] * ey[k] * H1[k][j]
        {
            float z[4][4];
            #pragma unroll
            for (int r = 0; r < 4; ++r)
                #pragma unroll
                for (int c = 0; c < 4; ++c) z[r][c] = 0.f;
            #pragma unroll 4
            for (int k = 0; k < 64; ++k) {
                float e = sV[k];
                float a0 = s1[k * LDP + 4 * ti + 0];
                float a1 = s1[k * LDP + 4 * ti + 1];
                float a2 = s1[k * LDP + 4 * ti + 2];
                float a3 = s1[k * LDP + 4 * ti + 3];
                float4 bv = *(const float4*)&s3[k * 64 + 4 * tj];
                bv.x *= e; bv.y *= e; bv.z *= e; bv.w *= e;
                FMA4(z[0], a0, bv); FMA4(z[1], a1, bv);
                FMA4(z[2], a2, bv); FMA4(z[3], a3, bv);
            }
            __syncthreads();   // s2 (NS tmp) dead
            #pragma unroll
            for (int r = 0; r < 4; ++r) {
                float4 v = {z[r][0], z[r][1], z[r][2], z[r][3]};
                *(float4*)&s2[(4 * ti + r) * 64 + 4 * tj] = v;
            }
        }
        __syncthreads();
        // C = Sinv * Z -> ws
        {
            float a[4][4];
            #pragma unroll
            for (int r = 0; r < 4; ++r)
                #pragma unroll
                for (int c = 0; c < 4; ++c) a[r][c] = 0.f;
            mm64<LDP, 64>(s1, s2, ti, tj, a);
            #pragma unroll
            for (int r = 0; r < 4; ++r) {
                float4 v = {a[r][0], a[r][1], a[r][2], a[r][3]};
                *(float4*)&ws[WS_C + (4 * ti + r) * 64 + 4 * tj] = v;
            }
        }
        __threadfence();
        __syncthreads();
        if (tid == 0) atomicAdd(ctr, 1u);
    } else if (b == 2) {
        float* s0 = lds;
        float* s1 = lds + 4352;
        float* s2 = lds + 8704;
        float* sV = lds + 16896;
        for (int idx = tid; idx < 1024; idx += 256) {
            int i = idx >> 4, j4 = (idx & 15) << 2;
            *(float4*)&s0[i * LDP + j4] = *(const float4*)&sx[i * 64 + j4];
        }
        if (tid < 64) sV[tid] = ex[tid];
        __syncthreads();
        ns_invert(s0, s1, s2, NS_SX, ti, tj, tid, 1.0f);   // P in s1
        float aR2[4][4], aR4[4][4], aT1[4][4];
        #pragma unroll
        for (int r = 0; r < 4; ++r)
            #pragma unroll
            for (int c = 0; c < 4; ++c) { aR2[r][c] = 0.f; aR4[r][c] = 0.f; aT1[r][c] = 0.f; }
        for (int k = 0; k < 64; ++k) {
            float e = sV[k], e2 = e * e;
            float4 av = *(const float4*)&s1[k * LDP + 4 * ti];
            float4 bv = *(const float4*)&s1[k * LDP + 4 * tj];
            float avv[4] = {av.x, av.y, av.z, av.w};
            #pragma unroll
            for (int r = 0; r < 4; ++r) {
                FMA4(aR4[r], avv[r], bv);
                float ea = e * avv[r];
                FMA4(aR2[r], ea, bv);
                float e2a = e2 * avv[r];
                FMA4(aT1[r], e2a, bv);
            }
        }
        #pragma unroll
        for (int r = 0; r < 4; ++r) {
            int o = (4 * ti + r) * 64 + 4 * tj;
            float4 v2 = {aR2[r][0], aR2[r][1], aR2[r][2], aR2[r][3]};
            float4 v4 = {aR4[r][0], aR4[r][1], aR4[r][2], aR4[r][3]};
            float4 v1 = {aT1[r][0], aT1[r][1], aT1[r][2], aT1[r][3]};
            *(float4*)&ws[WS_R2 + o] = v2;
            *(float4*)&ws[WS_R4 + o] = v4;
            *(float4*)&ws[WS_T1 + o] = v1;
        }
        __threadfence();
        __syncthreads();
        if (tid == 0) atomicAdd(ctr, 1u);
    } else if (b == 3) {
        float* s0 = lds;            // pad: A^T chunk
        float* s1 = lds + 4352;     // pad: Fy^T chunk
        float a[4][4];
        #pragma unroll
        for (int r = 0; r < 4; ++r)
            #pragma unroll
            for (int c = 0; c < 4; ++c) a[r][c] = 0.f;
        for (int ch = 0; ch < 4; ++ch) {
            for (int idx = tid; idx < 1024; idx += 256) {
                int i = idx >> 4, m4 = (idx & 15) << 2;
                float4 va = {0.f, 0.f, 0.f, 0.f}, vf = {0.f, 0.f, 0.f, 0.f};
                for (int s = 0; s < nparts; ++s) {
                    const float* p = ws + pbase + s * 32768;
                    float4 x = *(const float4*)&p[i * 256 + (ch << 6) + m4];
                    va.x += x.x; va.y += x.y; va.z += x.z; va.w += x.w;
                    float4 y = *(const float4*)&p[16384 + i * 256 + (ch << 6) + m4];
                    vf.x += y.x; vf.y += y.y; vf.z += y.z; vf.w += y.w;
                }
                s0[(m4 + 0) * LDP + i] = va.x; s0[(m4 + 1) * LDP + i] = va.y;
                s0[(m4 + 2) * LDP + i] = va.z; s0[(m4 + 3) * LDP + i] = va.w;
                s1[(m4 + 0) * LDP + i] = vf.x; s1[(m4 + 1) * LDP + i] = vf.y;
                s1[(m4 + 2) * LDP + i] = vf.z; s1[(m4 + 3) * LDP + i] = vf.w;
            }
            __syncthreads();
            for (int m = 0; m < 64; ++m) {
                float4 fv = *(const float4*)&s1[m * LDP + 4 * ti];
                float4 av = *(const float4*)&s0[m * LDP + 4 * tj];
                FMA4(a[0], fv.x, av); FMA4(a[1], fv.y, av);
                FMA4(a[2], fv.z, av); FMA4(a[3], fv.w, av);
            }
            __syncthreads();
        }
        #pragma unroll
        for (int r = 0; r < 4; ++r) {
            float4 v = {a[r][0], a[r][1], a[r][2], a[r][3]};
            *(float4*)&ws[WS_FYAT + (4 * ti + r) * 64 + 4 * tj] = v;
        }
        __threadfence();
        __syncthreads();
        if (tid == 0) atomicAdd(ctr, 1u);
    } else {
        // ---- block 0: G1 + Ginv prep, then barrier, then solve ----
        float* cM1   = lds;
        float* cR2   = lds + 4096;
        float* cR4   = lds + 8192;
        float* cGinv = lds + 12288;
        float* sE    = lds + 16384;  // flat (also NS tmp sYy)
        float* sX    = lds + 20480;  // pad  (also NS X sXx)
        float* cC    = lds + 24832;  // pad  (also A^T staging)
        float* sW    = lds + 29184;  // pad  (also G1)
        float* sV    = lds + 33536;  // 128
        float* sAT = cC;
        float* sG  = sW;
        float* sXx = sX;
        float* sYy = sE;
        // A-reduce + syrk -> G1
        {
            float a[4][4];
            #pragma unroll
            for (int r = 0; r < 4; ++r)
                #pragma unroll
                for (int c = 0; c < 4; ++c) a[r][c] = 0.f;
            for (int ch = 0; ch < 4; ++ch) {
                for (int idx = tid; idx < 1024; idx += 256) {
                    int i = idx >> 4, m4 = (idx & 15) << 2;
                    float4 va = {0.f, 0.f, 0.f, 0.f};
                    for (int s = 0; s < nparts; ++s) {
                        float4 x = *(const float4*)&ws[pbase + s * 32768 + i * 256 + (ch << 6) + m4];
                        va.x += x.x; va.y += x.y; va.z += x.z; va.w += x.w;
                    }
                    sAT[(m4 + 0) * LDP + i] = va.x; sAT[(m4 + 1) * LDP + i] = va.y;
                    sAT[(m4 + 2) * LDP + i] = va.z; sAT[(m4 + 3) * LDP + i] = va.w;
                }
                __syncthreads();
                for (int m = 0; m < 64; ++m) {
                    float4 av = *(const float4*)&sAT[m * LDP + 4 * ti];
                    float4 bv = *(const float4*)&sAT[m * LDP + 4 * tj];
                    FMA4(a[0], av.x, bv); FMA4(a[1], av.y, bv);
                    FMA4(a[2], av.z, bv); FMA4(a[3], av.w, bv);
                }
                __syncthreads();
            }
            #pragma unroll
            for (int r = 0; r < 4; ++r) {
                float4 v = {a[r][0], a[r][1], a[r][2], a[r][3]};
                *(float4*)&sG[(4 * ti + r) * LDP + 4 * tj] = v;
            }
        }
        __syncthreads();
        // Frobenius alpha = tr(G)/||G||_F^2
        if (tid < 64) {
            float s = 0.f;
            for (int j4 = 0; j4 < 64; j4 += 4) {
                float4 v = *(const float4*)&sG[tid * LDP + j4];
                s += v.x * v.x + v.y * v.y + v.z * v.z + v.w * v.w;
            }
            sV[tid] = s;
            sV[64 + tid] = sG[tid * LDP + tid];
        }
        __syncthreads();
        float f2 = 0.f, tr = 0.f;
        for (int i = 0; i < 64; ++i) { f2 += sV[i]; tr += sV[64 + i]; }
        ns_invert(sG, sXx, sYy, NS_G, ti, tj, tid, tr / f2);   // Ginv in sXx
        // barrier: wait for blocks 1..3
        if (tid == 0) {
            while (atomicAdd(ctr, 0u) < 3u) {}
            __threadfence();
        }
        __syncthreads();
        // build constants (cGinv <- sXx BEFORE sX zero; cM1 <- sG + l*T1)
        for (int idx = tid; idx < 1024; idx += 256) {
            int i = idx >> 4, j4 = (idx & 15) << 2;
            int o = i * 64 + j4;
            *(float4*)&cGinv[o] = *(const float4*)&sXx[i * LDP + j4];
            float4 g = *(const float4*)&sG[i * LDP + j4];
            float4 t = *(const float4*)&ws[WS_T1 + o];
            float4 m = {fmaf(LMBDA, t.x, g.x), fmaf(LMBDA, t.y, g.y),
                        fmaf(LMBDA, t.z, g.z), fmaf(LMBDA, t.w, g.w)};
            *(float4*)&cM1[o] = m;
            *(float4*)&cR2[o] = *(const float4*)&ws[WS_R2 + o];
            *(float4*)&cR4[o] = *(const float4*)&ws[WS_R4 + o];
        }
        __syncthreads();
        for (int idx = tid; idx < 1024; idx += 256) {
            int i = idx >> 4, j4 = (idx & 15) << 2;
            *(float4*)&cC[i * LDP + j4] = *(const float4*)&ws[WS_C + i * 64 + j4];
            float4 z = {0.f, 0.f, 0.f, 0.f};
            *(float4*)&sX[i * LDP + j4] = z;
        }
        float4 eyv = *(const float4*)&ey[4 * ti];
        float eyr[4] = {eyv.x, eyv.y, eyv.z, eyv.w};
        float leyr[4];
        #pragma unroll
        for (int r = 0; r < 4; ++r) leyr[r] = LMBDA * eyr[r];
        float fyr[4][4], xreg[4][4], E1[4][4];
        #pragma unroll
        for (int r = 0; r < 4; ++r) {
            float4 v = *(const float4*)&ws[WS_FYAT + (4 * ti + r) * 64 + 4 * tj];
            fyr[r][0] = v.x; fyr[r][1] = v.y; fyr[r][2] = v.z; fyr[r][3] = v.w;
            #pragma unroll
            for (int c = 0; c < 4; ++c) xreg[r][c] = 0.f;
        }
        __syncthreads();

        for (int it = 0; it < OUTER; ++it) {
            // grp1: Sm=X*M1, S2=X*R2, S4=X*R4 (shared A-reads)
            {
                float Sm[4][4], S2[4][4], S4[4][4];
                #pragma unroll
                for (int r = 0; r < 4; ++r)
                    #pragma unroll
                    for (int c = 0; c < 4; ++c) { Sm[r][c] = 0.f; S2[r][c] = 0.f; S4[r][c] = 0.f; }
                #pragma unroll 2
                for (int k = 0; k < 64; k += 4) {
                    float4 av[4];
                    #pragma unroll
                    for (int r = 0; r < 4; ++r)
                        av[r] = *(const float4*)&sX[(4 * ti + r) * LDP + k];
                    #pragma unroll
                    for (int q = 0; q < 4; ++q) {
                        float4 mv = *(const float4*)&cM1[(k + q) * 64 + 4 * tj];
                        float4 qv = *(const float4*)&cR2[(k + q) * 64 + 4 * tj];
                        float4 rv = *(const float4*)&cR4[(k + q) * 64 + 4 * tj];
                        float xq[4] = {av[0].x, av[1].x, av[2].x, av[3].x};
                        if (q == 1) { xq[0]=av[0].y; xq[1]=av[1].y; xq[2]=av[2].y; xq[3]=av[3].y; }
                        if (q == 2) { xq[0]=av[0].z; xq[1]=av[1].z; xq[2]=av[2].z; xq[3]=av[3].z; }
                        if (q == 3) { xq[0]=av[0].w; xq[1]=av[1].w; xq[2]=av[2].w; xq[3]=av[3].w; }
                        #pragma unroll
                        for (int r = 0; r < 4; ++r) {
                            FMA4(Sm[r], xq[r], mv);
                            FMA4(S2[r], xq[r], qv);
                            FMA4(S4[r], xq[r], rv);
                        }
                    }
                }
                #pragma unroll
                for (int r = 0; r < 4; ++r) {
                    float4 e2;
                    e2.x = LMBDA * fmaf(eyr[r], S4[r][0], -S2[r][0]);
                    e2.y = LMBDA * fmaf(eyr[r], S4[r][1], -S2[r][1]);
                    e2.z = LMBDA * fmaf(eyr[r], S4[r][2], -S2[r][2]);
                    e2.w = LMBDA * fmaf(eyr[r], S4[r][3], -S2[r][3]);
                    *(float4*)&sE[(4 * ti + r) * 64 + 4 * tj] = e2;
                    #pragma unroll
                    for (int c = 0; c < 4; ++c)
                        E1[r][c] = fmaf(-leyr[r], S2[r][c], Sm[r][c]);
                }
            }
            __syncthreads();
            // grp2: Z = C*E2 ; W = FyAT - E1 - Z
            {
                float Z[4][4];
                #pragma unroll
                for (int r = 0; r < 4; ++r)
                    #pragma unroll
                    for (int c = 0; c < 4; ++c) Z[r][c] = 0.f;
                mm64<LDP, 64>(cC, sE, ti, tj, Z);
                #pragma unroll
                for (int r = 0; r < 4; ++r) {
                    float4 w;
                    w.x = fyr[r][0] - E1[r][0] - Z[r][0];
                    w.y = fyr[r][1] - E1[r][1] - Z[r][1];
                    w.z = fyr[r][2] - E1[r][2] - Z[r][2];
                    w.w = fyr[r][3] - E1[r][3] - Z[r][3];
                    *(float4*)&sW[(4 * ti + r) * LDP + 4 * tj] = w;
                }
            }
            __syncthreads();
            // grp3: dX = W*Ginv ; X += dX
            {
                float dX[4][4];
                #pragma unroll
                for (int r = 0; r < 4; ++r)
                    #pragma unroll
                    for (int c = 0; c < 4; ++c) dX[r][c] = 0.f;
                mm64<LDP, 64>(sW, cGinv, ti, tj, dX);
                #pragma unroll
                for (int r = 0; r < 4; ++r) {
                    float4 v;
                    #pragma unroll
                    for (int c = 0; c < 4; ++c) xreg[r][c] += dX[r][c];
                    v.x = xreg[r][0]; v.y = xreg[r][1]; v.z = xreg[r][2]; v.w = xreg[r][3];
                    *(float4*)&sX[(4 * ti + r) * LDP + 4 * tj] = v;
                    if (it == OUTER - 1)
                        *(float4*)&out[(4 * ti + r) * 64 + 4 * tj] = v;
                }
            }
            if (it == OUTER - 1) break;
            __syncthreads();
        }
    }
}

extern "C" void kernel_launch(void* const* d_in, const int* in_sizes, int n_in,
                              void* d_out, int out_size, void* d_ws, size_t ws_size,
                              hipStream_t stream) {
    (void)in_sizes; (void)n_in; (void)out_size;
    const float* fx = (const float*)d_in[0];
    const float* fy = (const float*)d_in[1];
    const float* ex = (const float*)d_in[2];
    const float* ey = (const float*)d_in[3];
    const float* tx = (const float*)d_in[4];
    const float* ty = (const float*)d_in[5];
    const float* sx = (const float*)d_in[6];
    const float* sy = (const float*)d_in[7];
    float* ws = (float*)d_ws;
    float* out = (float*)d_out;

    const bool partial = ws_size >= (size_t)WS_NEED;
    const int nparts = partial ? SPLITS : 1;
    const int pbase = partial ? WS_PART : 0;

    (void)hipFuncSetAttribute((const void*)k23_fused,
                              hipFuncAttributeMaxDynamicSharedMemorySize, 134656);

    if (!partial)   // fallback: zero the atomic accumulation region
        (void)hipMemsetAsync(d_ws, 0, 2 * 64 * 256 * sizeof(float), stream);
    k1_gemm<<<dim3(8, partial ? SPLITS : 27), 256, 0, stream>>>(
        tx, fx, ty, fy, ws, nparts, pbase);
    k23_fused<<<4, 256, 134656, stream>>>(ws, sx, sy, ex, ey, out, nparts, pbase);
}

// Round 8
// 228.437 us; speedup vs baseline: 1.0249x; 1.0249x over previous
//
#include <hip/hip_runtime.h>

#define LMBDA 0.001f
#define NS_SY 4     // NS iters inv(sy): resid 0.8^16~0.03, enters lambda-damped C
#define NS_G  4     // NS iters inv(G1): right-preconditioner, rate-only error
#define NS_SX 4     // NS iters inv(sx): lambda-damped
#define OUTER 3     // outer Richardson iters
#define LDP 68      // padded stride for row-slice LDS matrices
#define SPLITS 8

// workspace layout (float offsets)
#define WS_G1   32768
#define WS_T1   36864
#define WS_R2   40960
#define WS_R4   45056
#define WS_GINV 49152
#define WS_C    53248
#define WS_FYAT 57344
#define WS_PART 61440   // SPLITS x 32768 (2 mats x 64x256) partial buffers
#define WS_NEED ((WS_PART + SPLITS * 32768) * 4)

#define FMA4(ar, xs, b) { ar[0]=fmaf((xs),(b).x,ar[0]); ar[1]=fmaf((xs),(b).y,ar[1]); \
                          ar[2]=fmaf((xs),(b).z,ar[2]); ar[3]=fmaf((xs),(b).w,ar[3]); }

// C-tile += A[4ti..][:] * B[:][4tj..]; all f4 (b128) LDS reads
template<int SA, int SB>
__device__ __forceinline__ void mm64(const float* __restrict__ A,
                                     const float* __restrict__ B,
                                     int ti, int tj, float a[4][4]) {
    #pragma unroll 4
    for (int k = 0; k < 64; k += 4) {
        float4 av0 = *(const float4*)&A[(4 * ti + 0) * SA + k];
        float4 av1 = *(const float4*)&A[(4 * ti + 1) * SA + k];
        float4 av2 = *(const float4*)&A[(4 * ti + 2) * SA + k];
        float4 av3 = *(const float4*)&A[(4 * ti + 3) * SA + k];
        float4 b0 = *(const float4*)&B[(k + 0) * SB + 4 * tj];
        float4 b1 = *(const float4*)&B[(k + 1) * SB + 4 * tj];
        float4 b2 = *(const float4*)&B[(k + 2) * SB + 4 * tj];
        float4 b3 = *(const float4*)&B[(k + 3) * SB + 4 * tj];
        FMA4(a[0], av0.x, b0); FMA4(a[0], av0.y, b1); FMA4(a[0], av0.z, b2); FMA4(a[0], av0.w, b3);
        FMA4(a[1], av1.x, b0); FMA4(a[1], av1.y, b1); FMA4(a[1], av1.z, b2); FMA4(a[1], av1.w, b3);
        FMA4(a[2], av2.x, b0); FMA4(a[2], av2.y, b1); FMA4(a[2], av2.z, b2); FMA4(a[2], av2.w, b3);
        FMA4(a[3], av3.x, b0); FMA4(a[3], av3.y, b1); FMA4(a[3], av3.z, b2); FMA4(a[3], av3.w, b3);
    }
}

// ---- Newton-Schulz: X <- X(2I - M X), X0 = alpha*I. sM,sX pad; sY flat ----
__device__ __forceinline__ void ns_invert(float* sM, float* sX, float* sY,
                                          int iters, int ti, int tj,
                                          int tid, float alpha)
{
    for (int idx = tid; idx < 4096; idx += 256) {
        int i = idx >> 6, j = idx & 63;
        sX[i * LDP + j] = (i == j) ? alpha : 0.f;
    }
    __syncthreads();
    for (int it = 0; it < iters; ++it) {
        float y[4][4];
        #pragma unroll
        for (int r = 0; r < 4; ++r)
            #pragma unroll
            for (int c = 0; c < 4; ++c) y[r][c] = 0.f;
        mm64<LDP, LDP>(sM, sX, ti, tj, y);
        #pragma unroll
        for (int r = 0; r < 4; ++r) {
            float4 v = {y[r][0], y[r][1], y[r][2], y[r][3]};
            *(float4*)&sY[(4 * ti + r) * 64 + 4 * tj] = v;
        }
        __syncthreads();
        float z[4][4];
        #pragma unroll
        for (int r = 0; r < 4; ++r)
            #pragma unroll
            for (int c = 0; c < 4; ++c) z[r][c] = 0.f;
        mm64<LDP, 64>(sX, sY, ti, tj, z);
        __syncthreads();
        #pragma unroll
        for (int r = 0; r < 4; ++r) {
            float4 xv = *(const float4*)&sX[(4 * ti + r) * LDP + 4 * tj];
            xv.x = 2.f * xv.x - z[r][0];
            xv.y = 2.f * xv.y - z[r][1];
            xv.z = 2.f * xv.z - z[r][2];
            xv.w = 2.f * xv.w - z[r][3];
            *(float4*)&sX[(4 * ti + r) * LDP + 4 * tj] = xv;
        }
        __syncthreads();
    }
}

// ---------------- Kernel 1: A = tx@fx, Fy = ty@fy  (64x5000 @ 5000x256) ----
// partial mode: grid (8, SPLITS), block stores its split's partial (no atomics)
// fallback:     grid (8, 27), atomicAdd into pre-zeroed region.
__global__ __launch_bounds__(256) void k1_gemm(
    const float* __restrict__ tx, const float* __restrict__ fx,
    const float* __restrict__ ty, const float* __restrict__ fy,
    float* __restrict__ ws, int nparts, int pbase)
{
    __shared__ float sT[64 * LDP];
    __shared__ float sF[64 * LDP];
    const int tid = threadIdx.x;
    const int ti = tid >> 4, tj = tid & 15;
    const int mat = blockIdx.x >> 2;
    const int m0 = (blockIdx.x & 3) << 6;
    const float* __restrict__ T = mat ? ty : tx;
    const float* __restrict__ F = mat ? fy : fx;
    float* __restrict__ Out = ws + pbase +
        (nparts > 1 ? (int)blockIdx.y * 32768 : 0) + mat * 16384;

    float acc[4][4];
    #pragma unroll
    for (int r = 0; r < 4; ++r)
        #pragma unroll
        for (int c = 0; c < 4; ++c) acc[r][c] = 0.f;

    for (int sc = blockIdx.y; sc * 64 < 5000; sc += gridDim.y) {
        const int v0 = sc << 6;
        int vlen = 5000 - v0; if (vlen > 64) vlen = 64;
        #pragma unroll
        for (int w = 0; w < 4; ++w) {
            const int fidx = tid + (w << 8);
            const int row = fidx >> 4, q = fidx & 15;
            const int vv = q << 2;
            if (vv < vlen) {
                float4 val = *(const float4*)(T + (size_t)row * 5000 + v0 + vv);
                sT[(vv + 0) * LDP + row] = val.x;
                sT[(vv + 1) * LDP + row] = val.y;
                sT[(vv + 2) * LDP + row] = val.z;
                sT[(vv + 3) * LDP + row] = val.w;
            }
            if (row < vlen) {
                *(float4*)&sF[row * LDP + (q << 2)] =
                    *(const float4*)(F + (size_t)(v0 + row) * 256 + m0 + (q << 2));
            }
        }
        __syncthreads();
        for (int v = 0; v < vlen; ++v) {
            float4 av = *(const float4*)&sT[v * LDP + 4 * ti];
            float4 bv = *(const float4*)&sF[v * LDP + 4 * tj];
            FMA4(acc[0], av.x, bv); FMA4(acc[1], av.y, bv);
            FMA4(acc[2], av.z, bv); FMA4(acc[3], av.w, bv);
        }
        __syncthreads();
    }
    if (nparts > 1) {
        #pragma unroll
        for (int r = 0; r < 4; ++r) {
            float4 v = {acc[r][0], acc[r][1], acc[r][2], acc[r][3]};
            *(float4*)&Out[(4 * ti + r) * 256 + m0 + 4 * tj] = v;
        }
    } else {
        #pragma unroll
        for (int r = 0; r < 4; ++r)
            #pragma unroll
            for (int c = 0; c < 4; ++c)
                atomicAdd(&Out[(4 * ti + r) * 256 + m0 + 4 * tj + c], acc[r][c]);
    }
}

// ---------------- Kernel 2: 4 specialized blocks (dyn LDS 69120 B) --------
// b0: A-reduce; G1 syrk -> ws; Ginv=NS4 (Frobenius alpha) -> ws
// b1: H1=sy^T sy; Sinv=NS(sy); C = Sinv*(Sinv^T D H1) -> ws
// b2: P=NS(sx); R2/R4/T1 -> ws        b3: A,Fy-reduce; FyAT -> ws
__global__ __launch_bounds__(256, 1) void k2_prep(
    float* __restrict__ ws,
    const float* __restrict__ sx, const float* __restrict__ sy,
    const float* __restrict__ ex, const float* __restrict__ ey,
    int nparts, int pbase)
{
    extern __shared__ __align__(16) float lds[];
    const int tid = threadIdx.x;
    const int ti = tid >> 4, tj = tid & 15;
    const int b = blockIdx.x;

    if (b == 0) {
        float* sAT = lds;            // pad: A^T chunk
        float* sG  = lds + 4352;     // pad: G1
        float* sX  = lds + 8704;     // pad: NS X -> Ginv
        float* sY  = lds + 13056;    // flat: NS tmp
        float* sV  = lds + 17152;    // 128: Frobenius reduce
        float a[4][4];
        #pragma unroll
        for (int r = 0; r < 4; ++r)
            #pragma unroll
            for (int c = 0; c < 4; ++c) a[r][c] = 0.f;
        for (int ch = 0; ch < 4; ++ch) {
            for (int idx = tid; idx < 1024; idx += 256) {
                int i = idx >> 4, m4 = (idx & 15) << 2;
                float4 va = {0.f, 0.f, 0.f, 0.f};
                for (int s = 0; s < nparts; ++s) {
                    float4 x = *(const float4*)&ws[pbase + s * 32768 + i * 256 + (ch << 6) + m4];
                    va.x += x.x; va.y += x.y; va.z += x.z; va.w += x.w;
                }
                sAT[(m4 + 0) * LDP + i] = va.x; sAT[(m4 + 1) * LDP + i] = va.y;
                sAT[(m4 + 2) * LDP + i] = va.z; sAT[(m4 + 3) * LDP + i] = va.w;
            }
            __syncthreads();
            for (int m = 0; m < 64; ++m) {
                float4 av = *(const float4*)&sAT[m * LDP + 4 * ti];
                float4 bv = *(const float4*)&sAT[m * LDP + 4 * tj];
                FMA4(a[0], av.x, bv); FMA4(a[1], av.y, bv);
                FMA4(a[2], av.z, bv); FMA4(a[3], av.w, bv);
            }
            __syncthreads();
        }
        #pragma unroll
        for (int r = 0; r < 4; ++r) {
            float4 v = {a[r][0], a[r][1], a[r][2], a[r][3]};
            *(float4*)&sG[(4 * ti + r) * LDP + 4 * tj] = v;
            *(float4*)&ws[WS_G1 + (4 * ti + r) * 64 + 4 * tj] = v;
        }
        __syncthreads();
        if (tid < 64) {
            float s = 0.f;
            for (int j4 = 0; j4 < 64; j4 += 4) {
                float4 v = *(const float4*)&sG[tid * LDP + j4];
                s += v.x * v.x + v.y * v.y + v.z * v.z + v.w * v.w;
            }
            sV[tid] = s;
            sV[64 + tid] = sG[tid * LDP + tid];
        }
        __syncthreads();
        float f2 = 0.f, tr = 0.f;
        for (int i = 0; i < 64; ++i) { f2 += sV[i]; tr += sV[64 + i]; }
        ns_invert(sG, sX, sY, NS_G, ti, tj, tid, tr / f2);
        for (int idx = tid; idx < 1024; idx += 256) {
            int i = idx >> 4, j4 = (idx & 15) << 2;
            *(float4*)&ws[WS_GINV + i * 64 + j4] = *(const float4*)&sX[i * LDP + j4];
        }
    } else if (b == 1) {
        float* s0 = lds;            // pad: sy
        float* s1 = lds + 4352;     // pad: NS X -> Sinv
        float* s2 = lds + 8704;     // flat: NS tmp -> Z
        float* s3 = lds + 12800;    // flat: H1
        float* sV = lds + 16896;    // ey
        for (int idx = tid; idx < 1024; idx += 256) {
            int i = idx >> 4, j4 = (idx & 15) << 2;
            *(float4*)&s0[i * LDP + j4] = *(const float4*)&sy[i * 64 + j4];
        }
        if (tid < 64) sV[tid] = ey[tid];
        __syncthreads();
        // H1 = sy^T sy (k-fixed outer product)
        {
            float h[4][4];
            #pragma unroll
            for (int r = 0; r < 4; ++r)
                #pragma unroll
                for (int c = 0; c < 4; ++c) h[r][c] = 0.f;
            for (int k = 0; k < 64; ++k) {
                float4 av = *(const float4*)&s0[k * LDP + 4 * ti];
                float4 bv = *(const float4*)&s0[k * LDP + 4 * tj];
                FMA4(h[0], av.x, bv); FMA4(h[1], av.y, bv);
                FMA4(h[2], av.z, bv); FMA4(h[3], av.w, bv);
            }
            #pragma unroll
            for (int r = 0; r < 4; ++r) {
                float4 v = {h[r][0], h[r][1], h[r][2], h[r][3]};
                *(float4*)&s3[(4 * ti + r) * 64 + 4 * tj] = v;
            }
        }
        __syncthreads();
        ns_invert(s0, s1, s2, NS_SY, ti, tj, tid, 1.0f);   // Sinv in s1
        // Z = Sinv^T * (D H1): Z[i][j] = sum_k Sinv[k][i] * ey[k] * H1[k][j]
        {
            float z[4][4];
            #pragma unroll
            for (int r = 0; r < 4; ++r)
                #pragma unroll
                for (int c = 0; c < 4; ++c) z[r][c] = 0.f;
            #pragma unroll 4
            for (int k = 0; k < 64; ++k) {
                float e = sV[k];
                float a0 = s1[k * LDP + 4 * ti + 0];
                float a1 = s1[k * LDP + 4 * ti + 1];
                float a2 = s1[k * LDP + 4 * ti + 2];
                float a3 = s1[k * LDP + 4 * ti + 3];
                float4 bv = *(const float4*)&s3[k * 64 + 4 * tj];
                bv.x *= e; bv.y *= e; bv.z *= e; bv.w *= e;
                FMA4(z[0], a0, bv); FMA4(z[1], a1, bv);
                FMA4(z[2], a2, bv); FMA4(z[3], a3, bv);
            }
            __syncthreads();   // NS tmp dead
            #pragma unroll
            for (int r = 0; r < 4; ++r) {
                float4 v = {z[r][0], z[r][1], z[r][2], z[r][3]};
                *(float4*)&s2[(4 * ti + r) * 64 + 4 * tj] = v;
            }
        }
        __syncthreads();
        // C = Sinv * Z -> ws
        {
            float a[4][4];
            #pragma unroll
            for (int r = 0; r < 4; ++r)
                #pragma unroll
                for (int c = 0; c < 4; ++c) a[r][c] = 0.f;
            mm64<LDP, 64>(s1, s2, ti, tj, a);
            #pragma unroll
            for (int r = 0; r < 4; ++r) {
                float4 v = {a[r][0], a[r][1], a[r][2], a[r][3]};
                *(float4*)&ws[WS_C + (4 * ti + r) * 64 + 4 * tj] = v;
            }
        }
    } else if (b == 2) {
        float* s0 = lds;
        float* s1 = lds + 4352;
        float* s2 = lds + 8704;
        float* sV = lds + 16896;
        for (int idx = tid; idx < 1024; idx += 256) {
            int i = idx >> 4, j4 = (idx & 15) << 2;
            *(float4*)&s0[i * LDP + j4] = *(const float4*)&sx[i * 64 + j4];
        }
        if (tid < 64) sV[tid] = ex[tid];
        __syncthreads();
        ns_invert(s0, s1, s2, NS_SX, ti, tj, tid, 1.0f);   // P in s1
        float aR2[4][4], aR4[4][4], aT1[4][4];
        #pragma unroll
        for (int r = 0; r < 4; ++r)
            #pragma unroll
            for (int c = 0; c < 4; ++c) { aR2[r][c] = 0.f; aR4[r][c] = 0.f; aT1[r][c] = 0.f; }
        for (int k = 0; k < 64; ++k) {
            float e = sV[k], e2 = e * e;
            float4 av = *(const float4*)&s1[k * LDP + 4 * ti];
            float4 bv = *(const float4*)&s1[k * LDP + 4 * tj];
            float avv[4] = {av.x, av.y, av.z, av.w};
            #pragma unroll
            for (int r = 0; r < 4; ++r) {
                FMA4(aR4[r], avv[r], bv);
                float ea = e * avv[r];
                FMA4(aR2[r], ea, bv);
                float e2a = e2 * avv[r];
                FMA4(aT1[r], e2a, bv);
            }
        }
        #pragma unroll
        for (int r = 0; r < 4; ++r) {
            int o = (4 * ti + r) * 64 + 4 * tj;
            float4 v2 = {aR2[r][0], aR2[r][1], aR2[r][2], aR2[r][3]};
            float4 v4 = {aR4[r][0], aR4[r][1], aR4[r][2], aR4[r][3]};
            float4 v1 = {aT1[r][0], aT1[r][1], aT1[r][2], aT1[r][3]};
            *(float4*)&ws[WS_R2 + o] = v2;
            *(float4*)&ws[WS_R4 + o] = v4;
            *(float4*)&ws[WS_T1 + o] = v1;
        }
    } else {
        float* s0 = lds;            // pad: A^T chunk
        float* s1 = lds + 4352;     // pad: Fy^T chunk
        float a[4][4];
        #pragma unroll
        for (int r = 0; r < 4; ++r)
            #pragma unroll
            for (int c = 0; c < 4; ++c) a[r][c] = 0.f;
        for (int ch = 0; ch < 4; ++ch) {
            for (int idx = tid; idx < 1024; idx += 256) {
                int i = idx >> 4, m4 = (idx & 15) << 2;
                float4 va = {0.f, 0.f, 0.f, 0.f}, vf = {0.f, 0.f, 0.f, 0.f};
                for (int s = 0; s < nparts; ++s) {
                    const float* p = ws + pbase + s * 32768;
                    float4 x = *(const float4*)&p[i * 256 + (ch << 6) + m4];
                    va.x += x.x; va.y += x.y; va.z += x.z; va.w += x.w;
                    float4 y = *(const float4*)&p[16384 + i * 256 + (ch << 6) + m4];
                    vf.x += y.x; vf.y += y.y; vf.z += y.z; vf.w += y.w;
                }
                s0[(m4 + 0) * LDP + i] = va.x; s0[(m4 + 1) * LDP + i] = va.y;
                s0[(m4 + 2) * LDP + i] = va.z; s0[(m4 + 3) * LDP + i] = va.w;
                s1[(m4 + 0) * LDP + i] = vf.x; s1[(m4 + 1) * LDP + i] = vf.y;
                s1[(m4 + 2) * LDP + i] = vf.z; s1[(m4 + 3) * LDP + i] = vf.w;
            }
            __syncthreads();
            for (int m = 0; m < 64; ++m) {
                float4 fv = *(const float4*)&s1[m * LDP + 4 * ti];
                float4 av = *(const float4*)&s0[m * LDP + 4 * tj];
                FMA4(a[0], fv.x, av); FMA4(a[1], fv.y, av);
                FMA4(a[2], fv.z, av); FMA4(a[3], fv.w, av);
            }
            __syncthreads();
        }
        #pragma unroll
        for (int r = 0; r < 4; ++r) {
            float4 v = {a[r][0], a[r][1], a[r][2], a[r][3]};
            *(float4*)&ws[WS_FYAT + (4 * ti + r) * 64 + 4 * tj] = v;
        }
    }
}

// ---------------- Kernel 3: hybrid residual Richardson (dyn 134144 B) -----
// X += (FyAT - E1 - C*E2)*Ginv ; E1 = X M1 - l D(X R2); E2 = l(D(X R4) - X R2)
__global__ __launch_bounds__(256, 1) void k3_solve(
    const float* __restrict__ ws, const float* __restrict__ ey_g,
    float* __restrict__ out)
{
    extern __shared__ __align__(16) float lds3[];
    float* cM1   = lds3;              // flat
    float* cR2   = lds3 + 4096;      // flat
    float* cR4   = lds3 + 8192;      // flat
    float* cGinv = lds3 + 12288;     // flat
    float* sE    = lds3 + 16384;     // flat (E2)
    float* sX    = lds3 + 20480;     // pad
    float* cC    = lds3 + 24832;     // pad
    float* sW    = lds3 + 29184;     // pad
    const int tid = threadIdx.x;
    const int ti = tid >> 4, tj = tid & 15;

    for (int idx = tid; idx < 1024; idx += 256) {
        int i = idx >> 4, j4 = (idx & 15) << 2;
        int o = i * 64 + j4;
        float4 g = *(const float4*)&ws[WS_G1 + o];
        float4 t = *(const float4*)&ws[WS_T1 + o];
        float4 m = {fmaf(LMBDA, t.x, g.x), fmaf(LMBDA, t.y, g.y),
                    fmaf(LMBDA, t.z, g.z), fmaf(LMBDA, t.w, g.w)};
        *(float4*)&cM1[o]   = m;
        *(float4*)&cR2[o]   = *(const float4*)&ws[WS_R2 + o];
        *(float4*)&cR4[o]   = *(const float4*)&ws[WS_R4 + o];
        *(float4*)&cGinv[o] = *(const float4*)&ws[WS_GINV + o];
        *(float4*)&cC[i * LDP + j4] = *(const float4*)&ws[WS_C + o];
        float4 z = {0.f, 0.f, 0.f, 0.f};
        *(float4*)&sX[i * LDP + j4] = z;
    }
    float4 eyv = *(const float4*)&ey_g[4 * ti];
    float eyr[4] = {eyv.x, eyv.y, eyv.z, eyv.w};
    float leyr[4];
    #pragma unroll
    for (int r = 0; r < 4; ++r) leyr[r] = LMBDA * eyr[r];

    float fyr[4][4], xreg[4][4], E1[4][4];
    #pragma unroll
    for (int r = 0; r < 4; ++r) {
        float4 v = *(const float4*)&ws[WS_FYAT + (4 * ti + r) * 64 + 4 * tj];
        fyr[r][0] = v.x; fyr[r][1] = v.y; fyr[r][2] = v.z; fyr[r][3] = v.w;
        #pragma unroll
        for (int c = 0; c < 4; ++c) xreg[r][c] = 0.f;
    }
    __syncthreads();

    for (int it = 0; it < OUTER; ++it) {
        // grp1: Sm=X*M1, S2=X*R2, S4=X*R4 (shared A-reads)
        {
            float Sm[4][4], S2[4][4], S4[4][4];
            #pragma unroll
            for (int r = 0; r < 4; ++r)
                #pragma unroll
                for (int c = 0; c < 4; ++c) { Sm[r][c] = 0.f; S2[r][c] = 0.f; S4[r][c] = 0.f; }
            #pragma unroll 2
            for (int k = 0; k < 64; k += 4) {
                float4 av[4];
                #pragma unroll
                for (int r = 0; r < 4; ++r)
                    av[r] = *(const float4*)&sX[(4 * ti + r) * LDP + k];
                #pragma unroll
                for (int q = 0; q < 4; ++q) {
                    float4 mv = *(const float4*)&cM1[(k + q) * 64 + 4 * tj];
                    float4 qv = *(const float4*)&cR2[(k + q) * 64 + 4 * tj];
                    float4 rv = *(const float4*)&cR4[(k + q) * 64 + 4 * tj];
                    float xq[4] = {av[0].x, av[1].x, av[2].x, av[3].x};
                    if (q == 1) { xq[0]=av[0].y; xq[1]=av[1].y; xq[2]=av[2].y; xq[3]=av[3].y; }
                    if (q == 2) { xq[0]=av[0].z; xq[1]=av[1].z; xq[2]=av[2].z; xq[3]=av[3].z; }
                    if (q == 3) { xq[0]=av[0].w; xq[1]=av[1].w; xq[2]=av[2].w; xq[3]=av[3].w; }
                    #pragma unroll
                    for (int r = 0; r < 4; ++r) {
                        FMA4(Sm[r], xq[r], mv);
                        FMA4(S2[r], xq[r], qv);
                        FMA4(S4[r], xq[r], rv);
                    }
                }
            }
            #pragma unroll
            for (int r = 0; r < 4; ++r) {
                float4 e2;
                e2.x = LMBDA * fmaf(eyr[r], S4[r][0], -S2[r][0]);
                e2.y = LMBDA * fmaf(eyr[r], S4[r][1], -S2[r][1]);
                e2.z = LMBDA * fmaf(eyr[r], S4[r][2], -S2[r][2]);
                e2.w = LMBDA * fmaf(eyr[r], S4[r][3], -S2[r][3]);
                *(float4*)&sE[(4 * ti + r) * 64 + 4 * tj] = e2;
                #pragma unroll
                for (int c = 0; c < 4; ++c)
                    E1[r][c] = fmaf(-leyr[r], S2[r][c], Sm[r][c]);
            }
        }
        __syncthreads();
        // grp2: Z = C*E2 ; W = FyAT - E1 - Z
        {
            float Z[4][4];
            #pragma unroll
            for (int r = 0; r < 4; ++r)
                #pragma unroll
                for (int c = 0; c < 4; ++c) Z[r][c] = 0.f;
            mm64<LDP, 64>(cC, sE, ti, tj, Z);
            #pragma unroll
            for (int r = 0; r < 4; ++r) {
                float4 w;
                w.x = fyr[r][0] - E1[r][0] - Z[r][0];
                w.y = fyr[r][1] - E1[r][1] - Z[r][1];
                w.z = fyr[r][2] - E1[r][2] - Z[r][2];
                w.w = fyr[r][3] - E1[r][3] - Z[r][3];
                *(float4*)&sW[(4 * ti + r) * LDP + 4 * tj] = w;
            }
        }
        __syncthreads();
        // grp3: dX = W*Ginv ; X += dX
        {
            float dX[4][4];
            #pragma unroll
            for (int r = 0; r < 4; ++r)
                #pragma unroll
                for (int c = 0; c < 4; ++c) dX[r][c] = 0.f;
            mm64<LDP, 64>(sW, cGinv, ti, tj, dX);
            #pragma unroll
            for (int r = 0; r < 4; ++r) {
                float4 v;
                #pragma unroll
                for (int c = 0; c < 4; ++c) xreg[r][c] += dX[r][c];
                v.x = xreg[r][0]; v.y = xreg[r][1]; v.z = xreg[r][2]; v.w = xreg[r][3];
                *(float4*)&sX[(4 * ti + r) * LDP + 4 * tj] = v;
                if (it == OUTER - 1)
                    *(float4*)&out[(4 * ti + r) * 64 + 4 * tj] = v;
            }
        }
        if (it == OUTER - 1) break;
        __syncthreads();
    }
}

extern "C" void kernel_launch(void* const* d_in, const int* in_sizes, int n_in,
                              void* d_out, int out_size, void* d_ws, size_t ws_size,
                              hipStream_t stream) {
    (void)in_sizes; (void)n_in; (void)out_size;
    const float* fx = (const float*)d_in[0];
    const float* fy = (const float*)d_in[1];
    const float* ex = (const float*)d_in[2];
    const float* ey = (const float*)d_in[3];
    const float* tx = (const float*)d_in[4];
    const float* ty = (const float*)d_in[5];
    const float* sx = (const float*)d_in[6];
    const float* sy = (const float*)d_in[7];
    float* ws = (float*)d_ws;
    float* out = (float*)d_out;

    const bool partial = ws_size >= (size_t)WS_NEED;
    const int nparts = partial ? SPLITS : 1;
    const int pbase = partial ? WS_PART : 0;

    (void)hipFuncSetAttribute((const void*)k2_prep,
                              hipFuncAttributeMaxDynamicSharedMemorySize, 69120);
    (void)hipFuncSetAttribute((const void*)k3_solve,
                              hipFuncAttributeMaxDynamicSharedMemorySize, 134144);

    if (!partial)   // fallback: zero the atomic accumulation region
        (void)hipMemsetAsync(d_ws, 0, 2 * 64 * 256 * sizeof(float), stream);
    k1_gemm<<<dim3(8, partial ? SPLITS : 27), 256, 0, stream>>>(
        tx, fx, ty, fy, ws, nparts, pbase);
    k2_prep<<<4, 256, 69120, stream>>>(ws, sx, sy, ex, ey, nparts, pbase);
    k3_solve<<<1, 256, 134144, stream>>>(ws, ey, out);
}

// Round 9
// 184.051 us; speedup vs baseline: 1.2721x; 1.2412x over previous
//
#include <hip/hip_runtime.h>

#define LMBDA 0.001f
#define NS_SY 4     // NS iters inv(sy): resid ~0.03, lambda-damped in C
#define NS_G  5     // NS iters inv(G1): rho0^32 ~ 5e-3 rate-only error
#define NS_SX 4     // NS iters inv(sx): lambda-damped
#define OUTER 3     // outer Richardson iters
#define LDP 68      // padded stride for row-slice LDS matrices
#define NK1 216     // k1-role blocks: 8 tiles x 27 V-splits

// workspace layout (float offsets)
#define WS_A    0        // 64*256 (atomic-accumulated)
#define WS_FY   16384    // 64*256
#define WS_CTR  32768    // barrier counter (zeroed by memset)
#define WS_G1   36864
#define WS_T1   40960
#define WS_R2   45056
#define WS_R4   49152
#define WS_GINV 53248
#define WS_C    57344
#define WS_FYAT 61440

#define FMA4(ar, xs, b) { ar[0]=fmaf((xs),(b).x,ar[0]); ar[1]=fmaf((xs),(b).y,ar[1]); \
                          ar[2]=fmaf((xs),(b).z,ar[2]); ar[3]=fmaf((xs),(b).w,ar[3]); }

// C-tile += A[4ti..][:] * B[:][4tj..]; all f4 (b128) LDS reads
template<int SA, int SB>
__device__ __forceinline__ void mm64(const float* __restrict__ A,
                                     const float* __restrict__ B,
                                     int ti, int tj, float a[4][4]) {
    #pragma unroll 4
    for (int k = 0; k < 64; k += 4) {
        float4 av0 = *(const float4*)&A[(4 * ti + 0) * SA + k];
        float4 av1 = *(const float4*)&A[(4 * ti + 1) * SA + k];
        float4 av2 = *(const float4*)&A[(4 * ti + 2) * SA + k];
        float4 av3 = *(const float4*)&A[(4 * ti + 3) * SA + k];
        float4 b0 = *(const float4*)&B[(k + 0) * SB + 4 * tj];
        float4 b1 = *(const float4*)&B[(k + 1) * SB + 4 * tj];
        float4 b2 = *(const float4*)&B[(k + 2) * SB + 4 * tj];
        float4 b3 = *(const float4*)&B[(k + 3) * SB + 4 * tj];
        FMA4(a[0], av0.x, b0); FMA4(a[0], av0.y, b1); FMA4(a[0], av0.z, b2); FMA4(a[0], av0.w, b3);
        FMA4(a[1], av1.x, b0); FMA4(a[1], av1.y, b1); FMA4(a[1], av1.z, b2); FMA4(a[1], av1.w, b3);
        FMA4(a[2], av2.x, b0); FMA4(a[2], av2.y, b1); FMA4(a[2], av2.z, b2); FMA4(a[2], av2.w, b3);
        FMA4(a[3], av3.x, b0); FMA4(a[3], av3.y, b1); FMA4(a[3], av3.z, b2); FMA4(a[3], av3.w, b3);
    }
}

// ---- Newton-Schulz: X <- X(2I - M X), X0 = alpha*I. sM,sX pad; sY flat ----
__device__ __forceinline__ void ns_invert(float* sM, float* sX, float* sY,
                                          int iters, int ti, int tj,
                                          int tid, float alpha)
{
    for (int idx = tid; idx < 4096; idx += 256) {
        int i = idx >> 6, j = idx & 63;
        sX[i * LDP + j] = (i == j) ? alpha : 0.f;
    }
    __syncthreads();
    for (int it = 0; it < iters; ++it) {
        float y[4][4];
        #pragma unroll
        for (int r = 0; r < 4; ++r)
            #pragma unroll
            for (int c = 0; c < 4; ++c) y[r][c] = 0.f;
        mm64<LDP, LDP>(sM, sX, ti, tj, y);
        #pragma unroll
        for (int r = 0; r < 4; ++r) {
            float4 v = {y[r][0], y[r][1], y[r][2], y[r][3]};
            *(float4*)&sY[(4 * ti + r) * 64 + 4 * tj] = v;
        }
        __syncthreads();
        float z[4][4];
        #pragma unroll
        for (int r = 0; r < 4; ++r)
            #pragma unroll
            for (int c = 0; c < 4; ++c) z[r][c] = 0.f;
        mm64<LDP, 64>(sX, sY, ti, tj, z);
        __syncthreads();
        #pragma unroll
        for (int r = 0; r < 4; ++r) {
            float4 xv = *(const float4*)&sX[(4 * ti + r) * LDP + 4 * tj];
            xv.x = 2.f * xv.x - z[r][0];
            xv.y = 2.f * xv.y - z[r][1];
            xv.z = 2.f * xv.z - z[r][2];
            xv.w = 2.f * xv.w - z[r][3];
            *(float4*)&sX[(4 * ti + r) * LDP + 4 * tj] = xv;
        }
        __syncthreads();
    }
}

// ---------------- Kernel 12: fused GEMM + prep (220 blocks) ----------------
// blocks 4..219: A=tx@fx, Fy=ty@fy via atomicAdd, then ctr++ (device barrier)
// blk1: H1=sy^T sy; Sinv=NS(sy); C=Sinv*(Sinv^T D H1)      [input-only deps]
// blk2: P=NS(sx); R2/R4/T1                                  [input-only deps]
// blk0: spin(ctr==NK1); G1=A A^T; Ginv=NS5 (Frobenius alpha)
// blk3: spin(ctr==NK1); FyAT=Fy A^T
__global__ __launch_bounds__(256, 1) void k12_fused(
    const float* __restrict__ tx, const float* __restrict__ fx,
    const float* __restrict__ ty, const float* __restrict__ fy,
    const float* __restrict__ sx, const float* __restrict__ sy,
    const float* __restrict__ ex, const float* __restrict__ ey,
    float* __restrict__ ws)
{
    extern __shared__ __align__(16) float lds[];
    const int tid = threadIdx.x;
    const int ti = tid >> 4, tj = tid & 15;
    const int bid = blockIdx.x;
    unsigned* ctr = (unsigned*)(ws + WS_CTR);

    if (bid >= 4) {
        // ---- k1 role: split-K GEMM chunk, atomic accumulate ----
        float* sT = lds;               // pad: T^T tile [v][k]
        float* sF = lds + 64 * LDP;    // pad: F tile  [v][m]
        const int g = bid - 4;
        const int bx = g & 7, by = g >> 3;          // by in [0,27)
        const int mat = bx >> 2;
        const int m0 = (bx & 3) << 6;
        const float* __restrict__ T = mat ? ty : tx;
        const float* __restrict__ F = mat ? fy : fx;
        float* __restrict__ Out = ws + (mat ? WS_FY : WS_A);

        float acc[4][4];
        #pragma unroll
        for (int r = 0; r < 4; ++r)
            #pragma unroll
            for (int c = 0; c < 4; ++c) acc[r][c] = 0.f;

        for (int sc = by; sc * 64 < 5000; sc += 27) {
            const int v0 = sc << 6;
            int vlen = 5000 - v0; if (vlen > 64) vlen = 64;
            #pragma unroll
            for (int w = 0; w < 4; ++w) {
                const int fidx = tid + (w << 8);
                const int row = fidx >> 4, q = fidx & 15;
                const int vv = q << 2;
                if (vv < vlen) {
                    float4 val = *(const float4*)(T + (size_t)row * 5000 + v0 + vv);
                    sT[(vv + 0) * LDP + row] = val.x;
                    sT[(vv + 1) * LDP + row] = val.y;
                    sT[(vv + 2) * LDP + row] = val.z;
                    sT[(vv + 3) * LDP + row] = val.w;
                }
                if (row < vlen) {
                    *(float4*)&sF[row * LDP + (q << 2)] =
                        *(const float4*)(F + (size_t)(v0 + row) * 256 + m0 + (q << 2));
                }
            }
            __syncthreads();
            for (int v = 0; v < vlen; ++v) {
                float4 av = *(const float4*)&sT[v * LDP + 4 * ti];
                float4 bv = *(const float4*)&sF[v * LDP + 4 * tj];
                FMA4(acc[0], av.x, bv); FMA4(acc[1], av.y, bv);
                FMA4(acc[2], av.z, bv); FMA4(acc[3], av.w, bv);
            }
            __syncthreads();
        }
        #pragma unroll
        for (int r = 0; r < 4; ++r)
            #pragma unroll
            for (int c = 0; c < 4; ++c)
                atomicAdd(&Out[(4 * ti + r) * 256 + m0 + 4 * tj + c], acc[r][c]);
        __threadfence();
        __syncthreads();
        if (tid == 0) atomicAdd(ctr, 1u);
    } else if (bid == 0) {
        // ---- G1 = A A^T; Ginv = NS5 ----
        float* sAT = lds;            // pad: A^T chunk
        float* sG  = lds + 4352;     // pad: G1
        float* sX  = lds + 8704;     // pad: NS X -> Ginv
        float* sY  = lds + 13056;    // flat: NS tmp
        float* sV  = lds + 17152;    // 128: Frobenius reduce
        if (tid == 0) { while (atomicAdd(ctr, 0u) < NK1) {} }
        __syncthreads();
        __threadfence();
        float a[4][4];
        #pragma unroll
        for (int r = 0; r < 4; ++r)
            #pragma unroll
            for (int c = 0; c < 4; ++c) a[r][c] = 0.f;
        for (int ch = 0; ch < 4; ++ch) {
            for (int idx = tid; idx < 1024; idx += 256) {
                int i = idx >> 4, m4 = (idx & 15) << 2;
                float4 x = *(const float4*)&ws[WS_A + i * 256 + (ch << 6) + m4];
                sAT[(m4 + 0) * LDP + i] = x.x; sAT[(m4 + 1) * LDP + i] = x.y;
                sAT[(m4 + 2) * LDP + i] = x.z; sAT[(m4 + 3) * LDP + i] = x.w;
            }
            __syncthreads();
            for (int m = 0; m < 64; ++m) {
                float4 av = *(const float4*)&sAT[m * LDP + 4 * ti];
                float4 bv = *(const float4*)&sAT[m * LDP + 4 * tj];
                FMA4(a[0], av.x, bv); FMA4(a[1], av.y, bv);
                FMA4(a[2], av.z, bv); FMA4(a[3], av.w, bv);
            }
            __syncthreads();
        }
        #pragma unroll
        for (int r = 0; r < 4; ++r) {
            float4 v = {a[r][0], a[r][1], a[r][2], a[r][3]};
            *(float4*)&sG[(4 * ti + r) * LDP + 4 * tj] = v;
            *(float4*)&ws[WS_G1 + (4 * ti + r) * 64 + 4 * tj] = v;
        }
        __syncthreads();
        if (tid < 64) {
            float s = 0.f;
            for (int j4 = 0; j4 < 64; j4 += 4) {
                float4 v = *(const float4*)&sG[tid * LDP + j4];
                s += v.x * v.x + v.y * v.y + v.z * v.z + v.w * v.w;
            }
            sV[tid] = s;
            sV[64 + tid] = sG[tid * LDP + tid];
        }
        __syncthreads();
        float f2 = 0.f, tr = 0.f;
        for (int i = 0; i < 64; ++i) { f2 += sV[i]; tr += sV[64 + i]; }
        ns_invert(sG, sX, sY, NS_G, ti, tj, tid, tr / f2);
        for (int idx = tid; idx < 1024; idx += 256) {
            int i = idx >> 4, j4 = (idx & 15) << 2;
            *(float4*)&ws[WS_GINV + i * 64 + j4] = *(const float4*)&sX[i * LDP + j4];
        }
    } else if (bid == 1) {
        // ---- H1, Sinv, C (input-only deps; overlaps k1) ----
        float* s0 = lds;            // pad: sy
        float* s1 = lds + 4352;     // pad: NS X -> Sinv
        float* s2 = lds + 8704;     // flat: NS tmp -> Z
        float* s3 = lds + 12800;    // flat: H1
        float* sV = lds + 16896;    // ey
        for (int idx = tid; idx < 1024; idx += 256) {
            int i = idx >> 4, j4 = (idx & 15) << 2;
            *(float4*)&s0[i * LDP + j4] = *(const float4*)&sy[i * 64 + j4];
        }
        if (tid < 64) sV[tid] = ey[tid];
        __syncthreads();
        {
            float h[4][4];
            #pragma unroll
            for (int r = 0; r < 4; ++r)
                #pragma unroll
                for (int c = 0; c < 4; ++c) h[r][c] = 0.f;
            for (int k = 0; k < 64; ++k) {
                float4 av = *(const float4*)&s0[k * LDP + 4 * ti];
                float4 bv = *(const float4*)&s0[k * LDP + 4 * tj];
                FMA4(h[0], av.x, bv); FMA4(h[1], av.y, bv);
                FMA4(h[2], av.z, bv); FMA4(h[3], av.w, bv);
            }
            #pragma unroll
            for (int r = 0; r < 4; ++r) {
                float4 v = {h[r][0], h[r][1], h[r][2], h[r][3]};
                *(float4*)&s3[(4 * ti + r) * 64 + 4 * tj] = v;
            }
        }
        __syncthreads();
        ns_invert(s0, s1, s2, NS_SY, ti, tj, tid, 1.0f);   // Sinv in s1
        // Z = Sinv^T * (D H1)
        {
            float z[4][4];
            #pragma unroll
            for (int r = 0; r < 4; ++r)
                #pragma unroll
                for (int c = 0; c < 4; ++c) z[r][c] = 0.f;
            #pragma unroll 4
            for (int k = 0; k < 64; ++k) {
                float e = sV[k];
                float a0 = s1[k * LDP + 4 * ti + 0];
                float a1 = s1[k * LDP + 4 * ti + 1];
                float a2 = s1[k * LDP + 4 * ti + 2];
                float a3 = s1[k * LDP + 4 * ti + 3];
                float4 bv = *(const float4*)&s3[k * 64 + 4 * tj];
                bv.x *= e; bv.y *= e; bv.z *= e; bv.w *= e;
                FMA4(z[0], a0, bv); FMA4(z[1], a1, bv);
                FMA4(z[2], a2, bv); FMA4(z[3], a3, bv);
            }
            __syncthreads();   // NS tmp dead
            #pragma unroll
            for (int r = 0; r < 4; ++r) {
                float4 v = {z[r][0], z[r][1], z[r][2], z[r][3]};
                *(float4*)&s2[(4 * ti + r) * 64 + 4 * tj] = v;
            }
        }
        __syncthreads();
        // C = Sinv * Z -> ws
        {
            float a[4][4];
            #pragma unroll
            for (int r = 0; r < 4; ++r)
                #pragma unroll
                for (int c = 0; c < 4; ++c) a[r][c] = 0.f;
            mm64<LDP, 64>(s1, s2, ti, tj, a);
            #pragma unroll
            for (int r = 0; r < 4; ++r) {
                float4 v = {a[r][0], a[r][1], a[r][2], a[r][3]};
                *(float4*)&ws[WS_C + (4 * ti + r) * 64 + 4 * tj] = v;
            }
        }
    } else if (bid == 2) {
        // ---- P = NS(sx); R2/R4/T1 (input-only deps) ----
        float* s0 = lds;
        float* s1 = lds + 4352;
        float* s2 = lds + 8704;
        float* sV = lds + 16896;
        for (int idx = tid; idx < 1024; idx += 256) {
            int i = idx >> 4, j4 = (idx & 15) << 2;
            *(float4*)&s0[i * LDP + j4] = *(const float4*)&sx[i * 64 + j4];
        }
        if (tid < 64) sV[tid] = ex[tid];
        __syncthreads();
        ns_invert(s0, s1, s2, NS_SX, ti, tj, tid, 1.0f);   // P in s1
        float aR2[4][4], aR4[4][4], aT1[4][4];
        #pragma unroll
        for (int r = 0; r < 4; ++r)
            #pragma unroll
            for (int c = 0; c < 4; ++c) { aR2[r][c] = 0.f; aR4[r][c] = 0.f; aT1[r][c] = 0.f; }
        for (int k = 0; k < 64; ++k) {
            float e = sV[k], e2 = e * e;
            float4 av = *(const float4*)&s1[k * LDP + 4 * ti];
            float4 bv = *(const float4*)&s1[k * LDP + 4 * tj];
            float avv[4] = {av.x, av.y, av.z, av.w};
            #pragma unroll
            for (int r = 0; r < 4; ++r) {
                FMA4(aR4[r], avv[r], bv);
                float ea = e * avv[r];
                FMA4(aR2[r], ea, bv);
                float e2a = e2 * avv[r];
                FMA4(aT1[r], e2a, bv);
            }
        }
        #pragma unroll
        for (int r = 0; r < 4; ++r) {
            int o = (4 * ti + r) * 64 + 4 * tj;
            float4 v2 = {aR2[r][0], aR2[r][1], aR2[r][2], aR2[r][3]};
            float4 v4 = {aR4[r][0], aR4[r][1], aR4[r][2], aR4[r][3]};
            float4 v1 = {aT1[r][0], aT1[r][1], aT1[r][2], aT1[r][3]};
            *(float4*)&ws[WS_R2 + o] = v2;
            *(float4*)&ws[WS_R4 + o] = v4;
            *(float4*)&ws[WS_T1 + o] = v1;
        }
    } else {
        // ---- bid == 3: FyAT = Fy A^T ----
        float* s0 = lds;            // pad: A^T chunk
        float* s1 = lds + 4352;     // pad: Fy^T chunk
        if (tid == 0) { while (atomicAdd(ctr, 0u) < NK1) {} }
        __syncthreads();
        __threadfence();
        float a[4][4];
        #pragma unroll
        for (int r = 0; r < 4; ++r)
            #pragma unroll
            for (int c = 0; c < 4; ++c) a[r][c] = 0.f;
        for (int ch = 0; ch < 4; ++ch) {
            for (int idx = tid; idx < 1024; idx += 256) {
                int i = idx >> 4, m4 = (idx & 15) << 2;
                float4 x = *(const float4*)&ws[WS_A + i * 256 + (ch << 6) + m4];
                s0[(m4 + 0) * LDP + i] = x.x; s0[(m4 + 1) * LDP + i] = x.y;
                s0[(m4 + 2) * LDP + i] = x.z; s0[(m4 + 3) * LDP + i] = x.w;
                float4 y = *(const float4*)&ws[WS_FY + i * 256 + (ch << 6) + m4];
                s1[(m4 + 0) * LDP + i] = y.x; s1[(m4 + 1) * LDP + i] = y.y;
                s1[(m4 + 2) * LDP + i] = y.z; s1[(m4 + 3) * LDP + i] = y.w;
            }
            __syncthreads();
            for (int m = 0; m < 64; ++m) {
                float4 fv = *(const float4*)&s1[m * LDP + 4 * ti];
                float4 av = *(const float4*)&s0[m * LDP + 4 * tj];
                FMA4(a[0], fv.x, av); FMA4(a[1], fv.y, av);
                FMA4(a[2], fv.z, av); FMA4(a[3], fv.w, av);
            }
            __syncthreads();
        }
        #pragma unroll
        for (int r = 0; r < 4; ++r) {
            float4 v = {a[r][0], a[r][1], a[r][2], a[r][3]};
            *(float4*)&ws[WS_FYAT + (4 * ti + r) * 64 + 4 * tj] = v;
        }
    }
}

// ---------------- Kernel 3: hybrid residual Richardson (dyn 134144 B) -----
// X += (FyAT - E1 - C*E2)*Ginv ; E1 = X M1 - l D(X R2); E2 = l(D(X R4) - X R2)
__global__ __launch_bounds__(256, 1) void k3_solve(
    const float* __restrict__ ws, const float* __restrict__ ey_g,
    float* __restrict__ out)
{
    extern __shared__ __align__(16) float lds3[];
    float* cM1   = lds3;              // flat
    float* cR2   = lds3 + 4096;      // flat
    float* cR4   = lds3 + 8192;      // flat
    float* cGinv = lds3 + 12288;     // flat
    float* sE    = lds3 + 16384;     // flat (E2)
    float* sX    = lds3 + 20480;     // pad
    float* cC    = lds3 + 24832;     // pad
    float* sW    = lds3 + 29184;     // pad
    const int tid = threadIdx.x;
    const int ti = tid >> 4, tj = tid & 15;

    for (int idx = tid; idx < 1024; idx += 256) {
        int i = idx >> 4, j4 = (idx & 15) << 2;
        int o = i * 64 + j4;
        float4 g = *(const float4*)&ws[WS_G1 + o];
        float4 t = *(const float4*)&ws[WS_T1 + o];
        float4 m = {fmaf(LMBDA, t.x, g.x), fmaf(LMBDA, t.y, g.y),
                    fmaf(LMBDA, t.z, g.z), fmaf(LMBDA, t.w, g.w)};
        *(float4*)&cM1[o]   = m;
        *(float4*)&cR2[o]   = *(const float4*)&ws[WS_R2 + o];
        *(float4*)&cR4[o]   = *(const float4*)&ws[WS_R4 + o];
        *(float4*)&cGinv[o] = *(const float4*)&ws[WS_GINV + o];
        *(float4*)&cC[i * LDP + j4] = *(const float4*)&ws[WS_C + o];
        float4 z = {0.f, 0.f, 0.f, 0.f};
        *(float4*)&sX[i * LDP + j4] = z;
    }
    float4 eyv = *(const float4*)&ey_g[4 * ti];
    float eyr[4] = {eyv.x, eyv.y, eyv.z, eyv.w};
    float leyr[4];
    #pragma unroll
    for (int r = 0; r < 4; ++r) leyr[r] = LMBDA * eyr[r];

    float fyr[4][4], xreg[4][4], E1[4][4];
    #pragma unroll
    for (int r = 0; r < 4; ++r) {
        float4 v = *(const float4*)&ws[WS_FYAT + (4 * ti + r) * 64 + 4 * tj];
        fyr[r][0] = v.x; fyr[r][1] = v.y; fyr[r][2] = v.z; fyr[r][3] = v.w;
        #pragma unroll
        for (int c = 0; c < 4; ++c) xreg[r][c] = 0.f;
    }
    __syncthreads();

    for (int it = 0; it < OUTER; ++it) {
        // grp1: Sm=X*M1, S2=X*R2, S4=X*R4 (shared A-reads)
        {
            float Sm[4][4], S2[4][4], S4[4][4];
            #pragma unroll
            for (int r = 0; r < 4; ++r)
                #pragma unroll
                for (int c = 0; c < 4; ++c) { Sm[r][c] = 0.f; S2[r][c] = 0.f; S4[r][c] = 0.f; }
            #pragma unroll 2
            for (int k = 0; k < 64; k += 4) {
                float4 av[4];
                #pragma unroll
                for (int r = 0; r < 4; ++r)
                    av[r] = *(const float4*)&sX[(4 * ti + r) * LDP + k];
                #pragma unroll
                for (int q = 0; q < 4; ++q) {
                    float4 mv = *(const float4*)&cM1[(k + q) * 64 + 4 * tj];
                    float4 qv = *(const float4*)&cR2[(k + q) * 64 + 4 * tj];
                    float4 rv = *(const float4*)&cR4[(k + q) * 64 + 4 * tj];
                    float xq[4] = {av[0].x, av[1].x, av[2].x, av[3].x};
                    if (q == 1) { xq[0]=av[0].y; xq[1]=av[1].y; xq[2]=av[2].y; xq[3]=av[3].y; }
                    if (q == 2) { xq[0]=av[0].z; xq[1]=av[1].z; xq[2]=av[2].z; xq[3]=av[3].z; }
                    if (q == 3) { xq[0]=av[0].w; xq[1]=av[1].w; xq[2]=av[2].w; xq[3]=av[3].w; }
                    #pragma unroll
                    for (int r = 0; r < 4; ++r) {
                        FMA4(Sm[r], xq[r], mv);
                        FMA4(S2[r], xq[r], qv);
                        FMA4(S4[r], xq[r], rv);
                    }
                }
            }
            #pragma unroll
            for (int r = 0; r < 4; ++r) {
                float4 e2;
                e2.x = LMBDA * fmaf(eyr[r], S4[r][0], -S2[r][0]);
                e2.y = LMBDA * fmaf(eyr[r], S4[r][1], -S2[r][1]);
                e2.z = LMBDA * fmaf(eyr[r], S4[r][2], -S2[r][2]);
                e2.w = LMBDA * fmaf(eyr[r], S4[r][3], -S2[r][3]);
                *(float4*)&sE[(4 * ti + r) * 64 + 4 * tj] = e2;
                #pragma unroll
                for (int c = 0; c < 4; ++c)
                    E1[r][c] = fmaf(-leyr[r], S2[r][c], Sm[r][c]);
            }
        }
        __syncthreads();
        // grp2: Z = C*E2 ; W = FyAT - E1 - Z
        {
            float Z[4][4];
            #pragma unroll
            for (int r = 0; r < 4; ++r)
                #pragma unroll
                for (int c = 0; c < 4; ++c) Z[r][c] = 0.f;
            mm64<LDP, 64>(cC, sE, ti, tj, Z);
            #pragma unroll
            for (int r = 0; r < 4; ++r) {
                float4 w;
                w.x = fyr[r][0] - E1[r][0] - Z[r][0];
                w.y = fyr[r][1] - E1[r][1] - Z[r][1];
                w.z = fyr[r][2] - E1[r][2] - Z[r][2];
                w.w = fyr[r][3] - E1[r][3] - Z[r][3];
                *(float4*)&sW[(4 * ti + r) * LDP + 4 * tj] = w;
            }
        }
        __syncthreads();
        // grp3: dX = W*Ginv ; X += dX
        {
            float dX[4][4];
            #pragma unroll
            for (int r = 0; r < 4; ++r)
                #pragma unroll
                for (int c = 0; c < 4; ++c) dX[r][c] = 0.f;
            mm64<LDP, 64>(sW, cGinv, ti, tj, dX);
            #pragma unroll
            for (int r = 0; r < 4; ++r) {
                float4 v;
                #pragma unroll
                for (int c = 0; c < 4; ++c) xreg[r][c] += dX[r][c];
                v.x = xreg[r][0]; v.y = xreg[r][1]; v.z = xreg[r][2]; v.w = xreg[r][3];
                *(float4*)&sX[(4 * ti + r) * LDP + 4 * tj] = v;
                if (it == OUTER - 1)
                    *(float4*)&out[(4 * ti + r) * 64 + 4 * tj] = v;
            }
        }
        if (it == OUTER - 1) break;
        __syncthreads();
    }
}

extern "C" void kernel_launch(void* const* d_in, const int* in_sizes, int n_in,
                              void* d_out, int out_size, void* d_ws, size_t ws_size,
                              hipStream_t stream) {
    (void)in_sizes; (void)n_in; (void)out_size; (void)ws_size;
    const float* fx = (const float*)d_in[0];
    const float* fy = (const float*)d_in[1];
    const float* ex = (const float*)d_in[2];
    const float* ey = (const float*)d_in[3];
    const float* tx = (const float*)d_in[4];
    const float* ty = (const float*)d_in[5];
    const float* sx = (const float*)d_in[6];
    const float* sy = (const float*)d_in[7];
    float* ws = (float*)d_ws;
    float* out = (float*)d_out;

    (void)hipFuncSetAttribute((const void*)k12_fused,
                              hipFuncAttributeMaxDynamicSharedMemorySize, 69120);
    (void)hipFuncSetAttribute((const void*)k3_solve,
                              hipFuncAttributeMaxDynamicSharedMemorySize, 134144);

    // zero wsA, wsFy (atomic targets) and the barrier counter
    (void)hipMemsetAsync(d_ws, 0, (2 * 64 * 256 + 16) * sizeof(float), stream);
    k12_fused<<<dim3(4 + NK1), 256, 69120, stream>>>(
        tx, fx, ty, fy, sx, sy, ex, ey, ws);
    k3_solve<<<1, 256, 134144, stream>>>(ws, ey, out);
}